// Round 3
// baseline (55.160 us; speedup 1.0000x reference)
//
#include <hip/hip_runtime.h>
#include <math.h>

// Problem constants (match reference setup_inputs)
#define BB 32
#define LL 1024
#define PP 8
#define DD 256
#define MARGIN_F 0.01f
// total = B * P * (L - P) = 32 * 8 * 1016
#define TOTAL_PAIRS 260096.0f

// ws layout (float offsets): [0] counter(uint), [64..95] qinv[32],
// [96..351] posSim[256], [512..2559] partial[2048]
#define WS_QINV 64
#define WS_POSSIM 96
#define WS_PARTIAL 512

// K1: per split b, compute the 8 positive-row cosine sims + 1/||q||.
// Block b: 8 pairs x 32 lanes; lane loads 8 floats (2x float4).
// Also zeroes the ticket counter for K2 (runs-before by stream order).
__global__ __launch_bounds__(256) void pos_kernel(const float* __restrict__ sent,
                                                  const float* __restrict__ query,
                                                  const int* __restrict__ pos_idx,
                                                  float* __restrict__ ws) {
    const int b    = blockIdx.x;
    const int pair = threadIdx.x >> 5;
    const int sub  = threadIdx.x & 31;
    if (b == 0 && threadIdx.x == 0) ((unsigned*)ws)[0] = 0u;

    const int idx = pos_idx[b * PP + pair];
    const float* xr = sent  + ((size_t)(b * LL + idx)) * DD;
    const float* qr = query + (size_t)b * DD;

    float dot = 0.f, nx = 0.f, nq = 0.f;
#pragma unroll
    for (int k = 0; k < 2; ++k) {
        const int off = (k * 32 + sub) * 4;
        const float4 x = *reinterpret_cast<const float4*>(xr + off);
        const float4 q = *reinterpret_cast<const float4*>(qr + off);
        dot += x.x * q.x + x.y * q.y + x.z * q.z + x.w * q.w;
        nx  += x.x * x.x + x.y * x.y + x.z * x.z + x.w * x.w;
        nq  += q.x * q.x + q.y * q.y + q.z * q.z + q.w * q.w;
    }
#pragma unroll
    for (int off = 16; off > 0; off >>= 1) {
        dot += __shfl_xor(dot, off, 32);
        nx  += __shfl_xor(nx,  off, 32);
        nq  += __shfl_xor(nq,  off, 32);
    }
    if (sub == 0) {
        const float dq = fmaxf(sqrtf(nq), 1e-12f);
        ws[WS_POSSIM + b * PP + pair] = dot / (fmaxf(sqrtf(nx), 1e-12f) * dq);
        if (pair == 0) ws[WS_QINV + b] = 1.0f / dq;
    }
}

// K2: the HBM-bound pass. 2048 blocks x 256 threads; block handles 16 rows
// (16 lanes/row, 16 floats/lane). Sim computed in registers, hinge folded in
// immediately against 8 register-resident positive sims. Last-block pattern
// (fence + int ticket) finishes the reduction — no third kernel.
__global__ __launch_bounds__(256) void main_kernel(const float* __restrict__ sent,
                                                   const float* __restrict__ query,
                                                   const int* __restrict__ pos_idx,
                                                   float* __restrict__ ws,
                                                   float* __restrict__ out) {
    const int blk = blockIdx.x;
    const int tid = threadIdx.x;
    const int b   = blk >> 6;                 // 64 blocks per split
    const int row = blk * 16 + (tid >> 4);    // global row in [0, B*L)
    const int seg = tid & 15;

    // positives in registers (uniform per block, L2-hot)
    float tpos[PP];
    int   pidr[PP];
#pragma unroll
    for (int p = 0; p < PP; ++p) {
        pidr[p] = pos_idx[b * PP + p];
        tpos[p] = ws[WS_POSSIM + b * PP + p] - MARGIN_F;  // s - pos + M = s - (pos - M)
    }
    const float qiv = ws[WS_QINV + b];

    const float* xr = sent  + (size_t)row * DD;
    const float* qr = query + (size_t)b   * DD;

    float dot = 0.f, nx = 0.f;
#pragma unroll
    for (int k = 0; k < 4; ++k) {
        const int off = (k * 16 + seg) * 4;
        const float4 x = *reinterpret_cast<const float4*>(xr + off);
        const float4 q = *reinterpret_cast<const float4*>(qr + off);
        dot += x.x * q.x + x.y * q.y + x.z * q.z + x.w * q.w;
        nx  += x.x * x.x + x.y * x.y + x.z * x.z + x.w * x.w;
    }
#pragma unroll
    for (int off = 8; off > 0; off >>= 1) {
        dot += __shfl_xor(dot, off, 16);
        nx  += __shfl_xor(nx,  off, 16);
    }

    float acc = 0.0f;
    if (seg == 0) {
        const float s = (dot * qiv) / fmaxf(sqrtf(nx), 1e-12f);
        const int l = row & (LL - 1);
        bool is_pos = false;
#pragma unroll
        for (int p = 0; p < PP; ++p) is_pos |= (l == pidr[p]);
        if (!is_pos) {
#pragma unroll
            for (int p = 0; p < PP; ++p) acc += fmaxf(s - tpos[p], 0.0f);
        }
    }

    // block reduce (acc nonzero only at seg==0 lanes)
#pragma unroll
    for (int off = 32; off > 0; off >>= 1) acc += __shfl_xor(acc, off, 64);

    __shared__ float wsum[4];
    __shared__ int lastflag;
    if ((tid & 63) == 0) wsum[tid >> 6] = acc;
    __syncthreads();
    if (tid == 0) {
        ws[WS_PARTIAL + blk] = wsum[0] + wsum[1] + wsum[2] + wsum[3];
        __threadfence();                                   // release partials
        const unsigned t = atomicAdd((unsigned*)ws, 1u);   // device-scope ticket
        lastflag = (t == (unsigned)(gridDim.x - 1));
    }
    __syncthreads();
    if (!lastflag) return;

    // last block: all 2048 partials are visible; fixed-order deterministic sum
    __threadfence();
    float s2 = 0.0f;
#pragma unroll
    for (int i = 0; i < 2; ++i) {
        const float4 v = *reinterpret_cast<const float4*>(ws + WS_PARTIAL + (tid + i * 256) * 4);
        s2 += v.x + v.y + v.z + v.w;
    }
#pragma unroll
    for (int off = 32; off > 0; off >>= 1) s2 += __shfl_xor(s2, off, 64);
    if ((tid & 63) == 0) wsum[tid >> 6] = s2;
    __syncthreads();
    if (tid == 0) out[0] = (wsum[0] + wsum[1] + wsum[2] + wsum[3]) / TOTAL_PAIRS;
}

extern "C" void kernel_launch(void* const* d_in, const int* in_sizes, int n_in,
                              void* d_out, int out_size, void* d_ws, size_t ws_size,
                              hipStream_t stream) {
    const float* sent  = (const float*)d_in[0];   // [B, L, D] f32
    const float* query = (const float*)d_in[1];   // [B, D]    f32
    const int*   pidx  = (const int*)d_in[2];     // [B, P]
    float* out = (float*)d_out;
    float* ws  = (float*)d_ws;

    pos_kernel <<<BB, 256, 0, stream>>>(sent, query, pidx, ws);
    main_kernel<<<(BB * LL) / 16, 256, 0, stream>>>(sent, query, pidx, ws, out);
}

// Round 4
// 13.929 us; speedup vs baseline: 3.9599x; 3.9599x over previous
//
#include <hip/hip_runtime.h>
#include <math.h>

// Problem constants (match reference setup_inputs)
#define BB 32
#define LL 1024
#define PP 8
#define DD 256
#define MARGIN_F 0.01f
// total = B * P * (L - P) = 32 * 8 * 1016
#define TOTAL_PAIRS 260096.0f
#define NBLK 1024   // 32 blocks per split, 32 rows per block

// K1: per block — (a) compute own split's 8 positive sims + q norm
// (redundant across the split's 32 blocks, but L2/L3-hot and removes a
// kernel node + all cross-block sync), (b) stream 32 rows, compute sim in
// registers, fold hinge vs 8 register-resident positives, (c) block-reduce,
// ONE plain store. No atomics, no fences — fully deterministic.
__global__ __launch_bounds__(256) void main_kernel(const float* __restrict__ sent,
                                                   const float* __restrict__ query,
                                                   const int* __restrict__ pos_idx,
                                                   float* __restrict__ partial) {
    const int blk   = blockIdx.x;
    const int b     = blk >> 5;   // split
    const int chunk = blk & 31;   // which 32-row slice of the split
    const int tid   = threadIdx.x;
    const int g     = tid >> 4;   // 16-lane group id (0..15)
    const int seg   = tid & 15;

    __shared__ float ldot[9];
    __shared__ float lnx[9];
    __shared__ int   lpid[PP];

    const float* qr = query + (size_t)b * DD;

    // ---- phase 1: groups 0..7 -> positive rows, group 8 -> q self-dot ----
    if (g < 9) {
        int prow = 0;
        if (g < PP) {
            prow = pos_idx[b * PP + g];
            if (seg == 0) lpid[g] = prow;
        }
        const float* xr = (g < PP) ? (sent + ((size_t)(b * LL + prow)) * DD) : qr;
        float dot = 0.f, nx = 0.f;
#pragma unroll
        for (int k = 0; k < 4; ++k) {
            const int off = (k * 16 + seg) * 4;
            const float4 x = *reinterpret_cast<const float4*>(xr + off);
            const float4 q = *reinterpret_cast<const float4*>(qr + off);
            dot += x.x * q.x + x.y * q.y + x.z * q.z + x.w * q.w;
            nx  += x.x * x.x + x.y * x.y + x.z * x.z + x.w * x.w;
        }
#pragma unroll
        for (int off = 8; off > 0; off >>= 1) {
            dot += __shfl_xor(dot, off, 16);
            nx  += __shfl_xor(nx,  off, 16);
        }
        if (seg == 0) { ldot[g] = dot; lnx[g] = nx; }
    }
    __syncthreads();

    const float qiv = 1.0f / fmaxf(sqrtf(lnx[8]), 1e-12f);
    float tpos[PP];   // pos_sim - margin, in registers
    int   pidr[PP];
#pragma unroll
    for (int p = 0; p < PP; ++p) {
        tpos[p] = (ldot[p] * qiv) / fmaxf(sqrtf(lnx[p]), 1e-12f) - MARGIN_F;
        pidr[p] = lpid[p];
    }

    // ---- phase 2: 32 rows, 16 lanes/row, hinge folded in registers ----
    float acc = 0.f;
#pragma unroll
    for (int it = 0; it < 2; ++it) {
        const int l = chunk * 32 + it * 16 + g;           // row within split
        const float* xr = sent + ((size_t)(b * LL + l)) * DD;
        float dot = 0.f, nx = 0.f;
#pragma unroll
        for (int k = 0; k < 4; ++k) {
            const int off = (k * 16 + seg) * 4;
            const float4 x = *reinterpret_cast<const float4*>(xr + off);
            const float4 q = *reinterpret_cast<const float4*>(qr + off);
            dot += x.x * q.x + x.y * q.y + x.z * q.z + x.w * q.w;
            nx  += x.x * x.x + x.y * x.y + x.z * x.z + x.w * x.w;
        }
#pragma unroll
        for (int off = 8; off > 0; off >>= 1) {
            dot += __shfl_xor(dot, off, 16);
            nx  += __shfl_xor(nx,  off, 16);
        }
        if (seg == 0) {
            const float s = (dot * qiv) / fmaxf(sqrtf(nx), 1e-12f);
            bool is_pos = false;
#pragma unroll
            for (int p = 0; p < PP; ++p) is_pos |= (l == pidr[p]);
            if (!is_pos) {
#pragma unroll
                for (int p = 0; p < PP; ++p) acc += fmaxf(s - tpos[p], 0.f);
            }
        }
    }

    // ---- block reduce, one store ----
#pragma unroll
    for (int off = 32; off > 0; off >>= 1) acc += __shfl_xor(acc, off, 64);
    __shared__ float wsum[4];
    if ((tid & 63) == 0) wsum[tid >> 6] = acc;
    __syncthreads();
    if (tid == 0) partial[blk] = wsum[0] + wsum[1] + wsum[2] + wsum[3];
}

// K2: fixed-order sum of 1024 partials, scale, write. All partials are
// rewritten by K1 every call, so no stale-workspace hazard.
__global__ __launch_bounds__(256) void final_kernel(const float* __restrict__ partial,
                                                    float* __restrict__ out) {
    const int tid = threadIdx.x;
    float s = 0.f;
#pragma unroll
    for (int i = 0; i < NBLK / 256; ++i) s += partial[tid + i * 256];
#pragma unroll
    for (int off = 32; off > 0; off >>= 1) s += __shfl_xor(s, off, 64);
    __shared__ float wsum[4];
    if ((tid & 63) == 0) wsum[tid >> 6] = s;
    __syncthreads();
    if (tid == 0) out[0] = (wsum[0] + wsum[1] + wsum[2] + wsum[3]) / TOTAL_PAIRS;
}

extern "C" void kernel_launch(void* const* d_in, const int* in_sizes, int n_in,
                              void* d_out, int out_size, void* d_ws, size_t ws_size,
                              hipStream_t stream) {
    const float* sent  = (const float*)d_in[0];   // [B, L, D] f32
    const float* query = (const float*)d_in[1];   // [B, D]    f32
    const int*   pidx  = (const int*)d_in[2];     // [B, P]
    float* out = (float*)d_out;
    float* partial = (float*)d_ws;                // NBLK floats

    main_kernel <<<NBLK, 256, 0, stream>>>(sent, query, pidx, partial);
    final_kernel<<<1, 256, 0, stream>>>(partial, out);
}

// Round 5
// 13.880 us; speedup vs baseline: 3.9741x; 1.0036x over previous
//
#include <hip/hip_runtime.h>
#include <math.h>

// Problem constants (match reference setup_inputs)
#define BB 32
#define LL 1024
#define PP 8
#define DD 256
#define MARGIN_F 0.01f
// total = B * P * (L - P) = 32 * 8 * 1016
#define TOTAL_PAIRS 260096.0f
#define NBLK 1024   // 32 blocks per split, 32 rows per block

// K1: per block — q held in registers (16 floats/lane; each 16-lane group
// spans all of D). Phase 1: groups 0..7 compute the split's 8 positive sims
// (redundant per block but L2-hot). Phase 2: stream 32 rows, 1 float4 load
// per k-step (x only — q comes from regs), fold hinge in registers,
// block-reduce, one plain store. No atomics, no fences.
__global__ __launch_bounds__(256) void main_kernel(const float* __restrict__ sent,
                                                   const float* __restrict__ query,
                                                   const int* __restrict__ pos_idx,
                                                   float* __restrict__ partial) {
    const int blk   = blockIdx.x;
    const int b     = blk >> 5;   // split
    const int chunk = blk & 31;   // 32-row slice within split
    const int tid   = threadIdx.x;
    const int g     = tid >> 4;   // 16-lane group (0..15)
    const int seg   = tid & 15;

    const float* qr = query + (size_t)b * DD;

    // q in registers: lane covers columns (k*16+seg)*4 .. +3, k=0..3
    float4 qv[4];
#pragma unroll
    for (int k = 0; k < 4; ++k)
        qv[k] = *reinterpret_cast<const float4*>(qr + (k * 16 + seg) * 4);

    // ||q||^2 from registers; identical reduction tree in every group -> bit-identical
    float nq = 0.f;
#pragma unroll
    for (int k = 0; k < 4; ++k)
        nq += qv[k].x * qv[k].x + qv[k].y * qv[k].y + qv[k].z * qv[k].z + qv[k].w * qv[k].w;
#pragma unroll
    for (int off = 8; off > 0; off >>= 1) nq += __shfl_xor(nq, off, 16);
    const float qiv = 1.0f / fmaxf(sqrtf(nq), 1e-12f);

    // ---- phase 1: groups 0..7 -> positive rows ----
    __shared__ float ldot[PP];
    __shared__ float lnx[PP];
    __shared__ int   lpid[PP];
    if (g < PP) {
        const int prow = pos_idx[b * PP + g];
        if (seg == 0) lpid[g] = prow;
        const float* xr = sent + ((size_t)(b * LL + prow)) * DD;
        float dot = 0.f, nx = 0.f;
#pragma unroll
        for (int k = 0; k < 4; ++k) {
            const float4 x = *reinterpret_cast<const float4*>(xr + (k * 16 + seg) * 4);
            dot += x.x * qv[k].x + x.y * qv[k].y + x.z * qv[k].z + x.w * qv[k].w;
            nx  += x.x * x.x + x.y * x.y + x.z * x.z + x.w * x.w;
        }
#pragma unroll
        for (int off = 8; off > 0; off >>= 1) {
            dot += __shfl_xor(dot, off, 16);
            nx  += __shfl_xor(nx,  off, 16);
        }
        if (seg == 0) { ldot[g] = dot; lnx[g] = nx; }
    }
    __syncthreads();

    float tpos[PP];   // pos_sim - margin, in registers
    int   pidr[PP];
#pragma unroll
    for (int p = 0; p < PP; ++p) {
        tpos[p] = (ldot[p] * qiv) / fmaxf(sqrtf(lnx[p]), 1e-12f) - MARGIN_F;
        pidr[p] = lpid[p];
    }

    // ---- phase 2: 32 rows, 16 lanes/row, single x load per k ----
    float acc = 0.f;
#pragma unroll
    for (int it = 0; it < 2; ++it) {
        const int l = chunk * 32 + it * 16 + g;           // row within split
        const float* xr = sent + ((size_t)(b * LL + l)) * DD;
        float dot = 0.f, nx = 0.f;
#pragma unroll
        for (int k = 0; k < 4; ++k) {
            const float4 x = *reinterpret_cast<const float4*>(xr + (k * 16 + seg) * 4);
            dot += x.x * qv[k].x + x.y * qv[k].y + x.z * qv[k].z + x.w * qv[k].w;
            nx  += x.x * x.x + x.y * x.y + x.z * x.z + x.w * x.w;
        }
#pragma unroll
        for (int off = 8; off > 0; off >>= 1) {
            dot += __shfl_xor(dot, off, 16);
            nx  += __shfl_xor(nx,  off, 16);
        }
        if (seg == 0) {
            const float s = (dot * qiv) / fmaxf(sqrtf(nx), 1e-12f);
            bool is_pos = false;
#pragma unroll
            for (int p = 0; p < PP; ++p) is_pos |= (l == pidr[p]);
            if (!is_pos) {
#pragma unroll
                for (int p = 0; p < PP; ++p) acc += fmaxf(s - tpos[p], 0.f);
            }
        }
    }

    // ---- block reduce, one store ----
#pragma unroll
    for (int off = 32; off > 0; off >>= 1) acc += __shfl_xor(acc, off, 64);
    __shared__ float wsum[4];
    if ((tid & 63) == 0) wsum[tid >> 6] = acc;
    __syncthreads();
    if (tid == 0) partial[blk] = wsum[0] + wsum[1] + wsum[2] + wsum[3];
}

// K2: fixed-order sum of 1024 partials (float4 per thread), scale, write.
__global__ __launch_bounds__(256) void final_kernel(const float* __restrict__ partial,
                                                    float* __restrict__ out) {
    const int tid = threadIdx.x;
    const float4 v = *reinterpret_cast<const float4*>(partial + tid * 4);
    float s = v.x + v.y + v.z + v.w;
#pragma unroll
    for (int off = 32; off > 0; off >>= 1) s += __shfl_xor(s, off, 64);
    __shared__ float wsum[4];
    if ((tid & 63) == 0) wsum[tid >> 6] = s;
    __syncthreads();
    if (tid == 0) out[0] = (wsum[0] + wsum[1] + wsum[2] + wsum[3]) / TOTAL_PAIRS;
}

extern "C" void kernel_launch(void* const* d_in, const int* in_sizes, int n_in,
                              void* d_out, int out_size, void* d_ws, size_t ws_size,
                              hipStream_t stream) {
    const float* sent  = (const float*)d_in[0];   // [B, L, D] f32
    const float* query = (const float*)d_in[1];   // [B, D]    f32
    const int*   pidx  = (const int*)d_in[2];     // [B, P]
    float* out = (float*)d_out;
    float* partial = (float*)d_ws;                // NBLK floats

    main_kernel <<<NBLK, 256, 0, stream>>>(sent, query, pidx, partial);
    final_kernel<<<1, 256, 0, stream>>>(partial, out);
}

// Round 6
// 13.245 us; speedup vs baseline: 4.1646x; 1.0479x over previous
//
#include <hip/hip_runtime.h>
#include <math.h>

// Problem constants (match reference setup_inputs)
#define BB 32
#define LL 1024
#define PP 8
#define DD 256
#define MARGIN_F 0.01f
// total = B * P * (L - P) = 32 * 8 * 1016
#define TOTAL_PAIRS 260096.0f
#define NBLK 1024   // 32 blocks per split, 32 rows per block

// K1: all loads issued up-front so positive-row latency overlaps the stream.
//  step 1: issue q loads (4 float4)
//  step 2: issue both phase-2 row loads (8 float4 -> registers)
//  step 3: groups 0..7 issue their positive-row loads (4 float4)
//  then: qiv, positive sims -> LDS, sync, hinge on register-held rows,
//  block-reduce, one plain store. No atomics, no fences.
__global__ __launch_bounds__(256) void main_kernel(const float* __restrict__ sent,
                                                   const float* __restrict__ query,
                                                   const int* __restrict__ pos_idx,
                                                   float* __restrict__ partial) {
    const int blk   = blockIdx.x;
    const int b     = blk >> 5;   // split
    const int chunk = blk & 31;   // 32-row slice within split
    const int tid   = threadIdx.x;
    const int g     = tid >> 4;   // 16-lane group (0..15)
    const int seg   = tid & 15;

    const float* qr = query + (size_t)b * DD;

    // ---- issue q loads ----
    float4 qv[4];
#pragma unroll
    for (int k = 0; k < 4; ++k)
        qv[k] = *reinterpret_cast<const float4*>(qr + (k * 16 + seg) * 4);

    // ---- issue both streamed-row loads (kept in registers) ----
    const int l0 = chunk * 32 + g;
    const int l1 = chunk * 32 + 16 + g;
    const float* x0 = sent + ((size_t)(b * LL + l0)) * DD;
    const float* x1 = sent + ((size_t)(b * LL + l1)) * DD;
    float4 xv0[4], xv1[4];
#pragma unroll
    for (int k = 0; k < 4; ++k) {
        xv0[k] = *reinterpret_cast<const float4*>(x0 + (k * 16 + seg) * 4);
        xv1[k] = *reinterpret_cast<const float4*>(x1 + (k * 16 + seg) * 4);
    }

    // ---- issue positive-row loads (groups 0..7) ----
    __shared__ float ltpos[PP];
    __shared__ int   lpid[PP];
    float4 pv[4];
    int prow = 0;
    if (g < PP) {
        prow = pos_idx[b * PP + g];
#pragma unroll
        for (int k = 0; k < 4; ++k)
            pv[k] = *reinterpret_cast<const float4*>(sent + ((size_t)(b * LL + prow)) * DD + (k * 16 + seg) * 4);
    }

    // ---- ||q||: register-only, identical tree per group -> bit-identical ----
    float nq = 0.f;
#pragma unroll
    for (int k = 0; k < 4; ++k)
        nq += qv[k].x * qv[k].x + qv[k].y * qv[k].y + qv[k].z * qv[k].z + qv[k].w * qv[k].w;
#pragma unroll
    for (int off = 8; off > 0; off >>= 1) nq += __shfl_xor(nq, off, 16);
    const float qiv = 1.0f / fmaxf(sqrtf(nq), 1e-12f);

    // ---- positive sims ----
    if (g < PP) {
        float dot = 0.f, nx = 0.f;
#pragma unroll
        for (int k = 0; k < 4; ++k) {
            dot += pv[k].x * qv[k].x + pv[k].y * qv[k].y + pv[k].z * qv[k].z + pv[k].w * qv[k].w;
            nx  += pv[k].x * pv[k].x + pv[k].y * pv[k].y + pv[k].z * pv[k].z + pv[k].w * pv[k].w;
        }
#pragma unroll
        for (int off = 8; off > 0; off >>= 1) {
            dot += __shfl_xor(dot, off, 16);
            nx  += __shfl_xor(nx,  off, 16);
        }
        if (seg == 0) {
            ltpos[g] = (dot * qiv) / fmaxf(sqrtf(nx), 1e-12f) - MARGIN_F;
            lpid[g]  = prow;
        }
    }
    __syncthreads();

    float tpos[PP];
    int   pidr[PP];
#pragma unroll
    for (int p = 0; p < PP; ++p) { tpos[p] = ltpos[p]; pidr[p] = lpid[p]; }

    // ---- consume the register-held rows ----
    float d0 = 0.f, n0 = 0.f, d1 = 0.f, n1 = 0.f;
#pragma unroll
    for (int k = 0; k < 4; ++k) {
        d0 += xv0[k].x * qv[k].x + xv0[k].y * qv[k].y + xv0[k].z * qv[k].z + xv0[k].w * qv[k].w;
        n0 += xv0[k].x * xv0[k].x + xv0[k].y * xv0[k].y + xv0[k].z * xv0[k].z + xv0[k].w * xv0[k].w;
        d1 += xv1[k].x * qv[k].x + xv1[k].y * qv[k].y + xv1[k].z * qv[k].z + xv1[k].w * qv[k].w;
        n1 += xv1[k].x * xv1[k].x + xv1[k].y * xv1[k].y + xv1[k].z * xv1[k].z + xv1[k].w * xv1[k].w;
    }
#pragma unroll
    for (int off = 8; off > 0; off >>= 1) {
        d0 += __shfl_xor(d0, off, 16);
        n0 += __shfl_xor(n0, off, 16);
        d1 += __shfl_xor(d1, off, 16);
        n1 += __shfl_xor(n1, off, 16);
    }

    float acc = 0.f;
    if (seg == 0) {
        const float s0 = (d0 * qiv) / fmaxf(sqrtf(n0), 1e-12f);
        const float s1 = (d1 * qiv) / fmaxf(sqrtf(n1), 1e-12f);
        bool p0 = false, p1 = false;
#pragma unroll
        for (int p = 0; p < PP; ++p) {
            p0 |= (l0 == pidr[p]);
            p1 |= (l1 == pidr[p]);
        }
        if (!p0) {
#pragma unroll
            for (int p = 0; p < PP; ++p) acc += fmaxf(s0 - tpos[p], 0.f);
        }
        if (!p1) {
#pragma unroll
            for (int p = 0; p < PP; ++p) acc += fmaxf(s1 - tpos[p], 0.f);
        }
    }

    // ---- block reduce, one store ----
#pragma unroll
    for (int off = 32; off > 0; off >>= 1) acc += __shfl_xor(acc, off, 64);
    __shared__ float wsum[4];
    if ((tid & 63) == 0) wsum[tid >> 6] = acc;
    __syncthreads();
    if (tid == 0) partial[blk] = wsum[0] + wsum[1] + wsum[2] + wsum[3];
}

// K2: fixed-order sum of 1024 partials (float4 per thread), scale, write.
__global__ __launch_bounds__(256) void final_kernel(const float* __restrict__ partial,
                                                    float* __restrict__ out) {
    const int tid = threadIdx.x;
    const float4 v = *reinterpret_cast<const float4*>(partial + tid * 4);
    float s = v.x + v.y + v.z + v.w;
#pragma unroll
    for (int off = 32; off > 0; off >>= 1) s += __shfl_xor(s, off, 64);
    __shared__ float wsum[4];
    if ((tid & 63) == 0) wsum[tid >> 6] = s;
    __syncthreads();
    if (tid == 0) out[0] = (wsum[0] + wsum[1] + wsum[2] + wsum[3]) / TOTAL_PAIRS;
}

extern "C" void kernel_launch(void* const* d_in, const int* in_sizes, int n_in,
                              void* d_out, int out_size, void* d_ws, size_t ws_size,
                              hipStream_t stream) {
    const float* sent  = (const float*)d_in[0];   // [B, L, D] f32
    const float* query = (const float*)d_in[1];   // [B, D]    f32
    const int*   pidx  = (const int*)d_in[2];     // [B, P]
    float* out = (float*)d_out;
    float* partial = (float*)d_ws;                // NBLK floats

    main_kernel <<<NBLK, 256, 0, stream>>>(sent, query, pidx, partial);
    final_kernel<<<1, 256, 0, stream>>>(partial, out);
}